// Round 4
// baseline (598.764 us; speedup 1.0000x reference)
//
#include <hip/hip_runtime.h>
#include <math.h>

#define N_NODES   262144
#define N_EDGES   4194304
#define NUM_GRAPHS 1024
#define NB        512          // coarse buckets (dst >> 9)
#define BN        512          // nodes per bucket

static __device__ __forceinline__ float sigmoidf_(float v) {
    return 1.0f / (1.0f + __expf(-v));
}

// ---------------------------------------------------------------------------
// K0: pack node records: nrec[n] = {x0,x1,x2,x3, p0,p1,p2, 0}  (32 B aligned)
// ---------------------------------------------------------------------------
__global__ __launch_bounds__(256) void pack_kernel(
    const float* __restrict__ x, const float* __restrict__ pos,
    float* __restrict__ nrec)
{
    int n = blockIdx.x * 256 + threadIdx.x;
    float4 xv = *(const float4*)(x + 4*n);
    float p0 = pos[3*n], p1 = pos[3*n+1], p2 = pos[3*n+2];
    float4* o = (float4*)(nrec + 8*n);
    o[0] = xv;
    o[1] = make_float4(p0, p1, p2, 0.0f);
}

// ---------------------------------------------------------------------------
// K1: coarse bucket histogram. 256 blocks x 256 thr x 64 edges.
// ---------------------------------------------------------------------------
__global__ __launch_bounds__(256) void bucket_hist_kernel(
    const int* __restrict__ ei, int* __restrict__ bucket_total)
{
    __shared__ int cnt[NB];
    cnt[threadIdx.x] = 0; cnt[threadIdx.x + 256] = 0;
    __syncthreads();
    int base = blockIdx.x * 16384;
    #pragma unroll 4
    for (int i = 0; i < 64; ++i) {
        int dst = ei[N_EDGES + base + i*256 + threadIdx.x];
        atomicAdd(&cnt[dst >> 9], 1);
    }
    __syncthreads();
    int c0 = cnt[threadIdx.x], c1 = cnt[threadIdx.x + 256];
    if (c0) atomicAdd(bucket_total + threadIdx.x, c0);
    if (c1) atomicAdd(bucket_total + threadIdx.x + 256, c1);
}

// ---------------------------------------------------------------------------
// K2: exclusive scan of 512 bucket totals -> bucket_base, bucket_cursor.
// ---------------------------------------------------------------------------
__global__ __launch_bounds__(512) void bucket_scan_kernel(
    const int* __restrict__ bucket_total,
    int* __restrict__ bucket_base, int* __restrict__ bucket_cursor)
{
    int i = threadIdx.x;
    int v = bucket_total[i];
    int lane = i & 63, wid = i >> 6;
    int s = v;
    #pragma unroll
    for (int o = 1; o < 64; o <<= 1) {
        int t = __shfl_up(s, o);
        if (lane >= o) s += t;
    }
    __shared__ int ws[8];
    if (lane == 63) ws[wid] = s;
    __syncthreads();
    int b = 0;
    #pragma unroll
    for (int w = 0; w < 8; ++w) if (w < wid) b += ws[w];
    int excl = b + s - v;
    bucket_base[i]   = excl;
    bucket_cursor[i] = excl;
}

// ---------------------------------------------------------------------------
// K3: binning. 1024 blocks x 256 thr x 16 edges. Pack (dst&511)<<18 | src.
// ---------------------------------------------------------------------------
__global__ __launch_bounds__(256) void binning_kernel(
    const int* __restrict__ ei, int* __restrict__ bucket_cursor,
    int* __restrict__ staged)
{
    __shared__ int cnt[NB];
    __shared__ int runbase[NB];
    cnt[threadIdx.x] = 0; cnt[threadIdx.x + 256] = 0;
    __syncthreads();

    int base = blockIdx.x * 4096;
    int ds[16];
    #pragma unroll
    for (int i = 0; i < 16; ++i) {
        ds[i] = ei[N_EDGES + base + i*256 + threadIdx.x];
        atomicAdd(&cnt[ds[i] >> 9], 1);
    }
    __syncthreads();
    {
        int k0 = threadIdx.x, k1 = threadIdx.x + 256;
        int c0 = cnt[k0], c1 = cnt[k1];
        runbase[k0] = c0 ? atomicAdd(bucket_cursor + k0, c0) : 0;
        runbase[k1] = c1 ? atomicAdd(bucket_cursor + k1, c1) : 0;
        cnt[k0] = 0; cnt[k1] = 0;
    }
    __syncthreads();
    #pragma unroll
    for (int i = 0; i < 16; ++i) {
        int e   = base + i*256 + threadIdx.x;
        int src = ei[e];
        int dst = ds[i];
        int bk  = dst >> 9;
        int r   = atomicAdd(&cnt[bk], 1);
        staged[runbase[bk] + r] = ((dst & 511) << 18) | src;
    }
}

// ---------------------------------------------------------------------------
// K4 (fused, per-bucket): edge-parallel edge-MLP with LDS accumulation, then
// node MLP + softmax + attention pooling. 512 blocks, 512 threads.
// ---------------------------------------------------------------------------
__global__ __launch_bounds__(512) void fused_bucket_kernel(
    const float* __restrict__ nrec,
    const int* __restrict__ staged, const int* __restrict__ bucket_base,
    const int* __restrict__ bucket_total, const int* __restrict__ batch,
    const float* __restrict__ w1, const float* __restrict__ b1,
    const float* __restrict__ w2, const float* __restrict__ b2,
    const float* __restrict__ pw, const float* __restrict__ pb,
    float* __restrict__ s_out, float* __restrict__ pooled)
{
    __shared__ float S[BN*17];          // 16 acc + 1 count, stride 17 (odd)
    __shared__ float drec[BN*9];        // dst records, stride 9 (odd)
    __shared__ __align__(16) float sw1[144];
    __shared__ float sb1[16];
    __shared__ __align__(16) float sw2[256];
    __shared__ float sb2[16];
    __shared__ float spw[32];
    __shared__ float spb[2];

    int tid = threadIdx.x;
    if (tid < 144) sw1[tid] = w1[tid];
    if (tid >= 144 && tid < 160) sb1[tid - 144] = b1[tid - 144];
    if (tid >= 160 && tid < 176) sb2[tid - 160] = b2[tid - 160];
    if (tid >= 176 && tid < 208) spw[tid - 176] = pw[tid - 176];
    if (tid >= 208 && tid < 210) spb[tid - 208] = pb[tid - 208];
    if (tid >= 256) sw2[tid - 256] = w2[tid - 256];

    for (int i = tid; i < BN*17; i += 512) S[i] = 0.0f;

    int bkt   = blockIdx.x;
    int nbase = bkt * BN;
    // stage this bucket's dst records (coalesced global read)
    for (int i = tid; i < BN*8; i += 512) {
        int node = i >> 3, k = i & 7;
        drec[node*9 + k] = nrec[(size_t)nbase*8 + i];
    }
    __syncthreads();

    int gbase = bucket_base[bkt];
    int ecnt  = bucket_total[bkt];

    for (int i = tid; i < ecnt; i += 512) {
        int p   = staged[gbase + i];
        int lo  = p >> 18;
        int src = p & 0x3FFFF;
        float4 xs = *(const float4*)(nrec + 8*src);
        float4 ps = *(const float4*)(nrec + 8*src + 4);
        const float* dr = drec + lo*9;
        float px = ps.x - dr[4];
        float py = ps.y - dr[5];
        float pz = ps.z - dr[6];
        float dist = sqrtf(px*px + py*py + pz*pz);
        float feat[9] = {dr[0], dr[1], dr[2], dr[3], xs.x, xs.y, xs.z, xs.w, dist};

        float h[16];
        #pragma unroll
        for (int j = 0; j < 16; ++j) h[j] = sb1[j];
        #pragma unroll
        for (int q = 0; q < 9; ++q) {
            float f = feat[q];
            #pragma unroll
            for (int j4 = 0; j4 < 4; ++j4) {
                float4 w = *(const float4*)&sw1[q*16 + 4*j4];
                h[4*j4+0] = fmaf(f, w.x, h[4*j4+0]);
                h[4*j4+1] = fmaf(f, w.y, h[4*j4+1]);
                h[4*j4+2] = fmaf(f, w.z, h[4*j4+2]);
                h[4*j4+3] = fmaf(f, w.w, h[4*j4+3]);
            }
        }
        float* Sr = S + lo*17;
        #pragma unroll
        for (int j = 0; j < 16; ++j) {
            float v = h[j];
            atomicAdd(Sr + j, v * sigmoidf_(v));
        }
        atomicAdd(Sr + 16, 1.0f);
    }
    __syncthreads();

    // ---- node phase: one thread per node ----
    int t = tid;                 // 0..511
    const float* Sr = S + t*17;
    float c   = Sr[16];
    float inv = 1.0f / fmaxf(c, 1.0f);

    float h[16];
    #pragma unroll
    for (int j = 0; j < 16; ++j) h[j] = c * sb2[j];
    #pragma unroll
    for (int q = 0; q < 16; ++q) {
        float f = Sr[q];
        #pragma unroll
        for (int j4 = 0; j4 < 4; ++j4) {
            float4 w = *(const float4*)&sw2[q*16 + 4*j4];
            h[4*j4+0] = fmaf(f, w.x, h[4*j4+0]);
            h[4*j4+1] = fmaf(f, w.y, h[4*j4+1]);
            h[4*j4+2] = fmaf(f, w.z, h[4*j4+2]);
            h[4*j4+3] = fmaf(f, w.w, h[4*j4+3]);
        }
    }
    #pragma unroll
    for (int j = 0; j < 16; ++j) h[j] = fmaxf(h[j] * inv, 0.0f);

    float l0 = spb[0], l1 = spb[1];
    #pragma unroll
    for (int j = 0; j < 16; ++j) {
        l0 = fmaf(h[j], spw[2*j+0], l0);
        l1 = fmaf(h[j], spw[2*j+1], l1);
    }
    float m = fmaxf(l0, l1);
    float e0 = __expf(l0 - m), e1 = __expf(l1 - m);
    float r = 1.0f / (e0 + e1);
    float s0 = e0 * r, s1 = e1 * r;

    int n = nbase + t;
    *(float2*)(s_out + 2*n) = make_float2(s0, s1);

    float w[32];
    #pragma unroll
    for (int j = 0; j < 16; ++j) { w[j] = s0 * h[j]; w[16+j] = s1 * h[j]; }

    int b = batch[n];
    int lane = t & 63;
    #pragma unroll
    for (int o = 1; o < 64; o <<= 1) {
        int bn = __shfl_down(b, o);
        bool take = (lane + o < 64) && (bn == b);
        #pragma unroll
        for (int cc = 0; cc < 32; ++cc) {
            float vn = __shfl_down(w[cc], o);
            if (take) w[cc] += vn;
        }
    }
    int bp = __shfl_up(b, 1);
    if (lane == 0 || bp != b) {
        float* pg = pooled + 32*b;
        #pragma unroll
        for (int cc = 0; cc < 32; ++cc) unsafeAtomicAdd(pg + cc, w[cc]);
    }
}

// ---------------------------------------------------------------------------
// K5: per-graph heads. z, recon, analytic potential + forces.
// ---------------------------------------------------------------------------
__global__ __launch_bounds__(256) void graph_kernel(
    const float* __restrict__ pooled,
    const float* __restrict__ toz_w, const float* __restrict__ toz_b,
    const float* __restrict__ vp_w1, const float* __restrict__ vp_b1,
    const float* __restrict__ vp_w2, const float* __restrict__ vp_b2,
    const float* __restrict__ bridge_w, const float* __restrict__ bridge_b,
    float* __restrict__ out_recon, float* __restrict__ out_z,
    float* __restrict__ out_forces, float* __restrict__ out_V)
{
    int g = blockIdx.x * 256 + threadIdx.x;
    if (g >= NUM_GRAPHS) return;

    const float* P = pooled + 32*g;
    float z[8];
    #pragma unroll
    for (int k = 0; k < 2; ++k) {
        #pragma unroll
        for (int d = 0; d < 4; ++d) {
            float a = toz_b[d];
            #pragma unroll
            for (int i = 0; i < 16; ++i) a = fmaf(P[16*k+i], toz_w[4*i+d], a);
            z[4*k+d] = a;
        }
    }
    #pragma unroll
    for (int i = 0; i < 8; ++i) out_z[8*g+i] = z[i];

    #pragma unroll
    for (int j = 0; j < 32; ++j) {
        float a = bridge_b[j];
        #pragma unroll
        for (int i = 0; i < 8; ++i) a = fmaf(z[i], bridge_w[32*i+j], a);
        out_recon[32*g+j] = a;
    }

    float d0 = z[0]-z[4], d1 = z[1]-z[5];
    float dd = sqrtf(d0*d0 + d1*d1 + 1e-6f);

    float V = vp_b2[0];
    float dV = 0.0f;
    #pragma unroll
    for (int j = 0; j < 32; ++j) {
        float w1 = vp_w1[j];
        float t  = fmaf(dd, w1, vp_b1[j]);
        float et = __expf(t);
        float sp = __logf(1.0f + et);
        float sg = et / (1.0f + et);
        float w2 = vp_w2[j];
        V  = fmaf(sp, w2, V);
        dV = fmaf(sg * w1, w2, dV);
    }
    out_V[g] = V;

    float scale = dV / dd;
    float gx = scale * d0, gy = scale * d1;
    out_forces[4*g+0] = -gx;
    out_forces[4*g+1] = -gy;
    out_forces[4*g+2] =  gx;
    out_forces[4*g+3] =  gy;
}

// ---------------------------------------------------------------------------
extern "C" void kernel_launch(void* const* d_in, const int* in_sizes, int n_in,
                              void* d_out, int out_size, void* d_ws, size_t ws_size,
                              hipStream_t stream) {
    const float* x        = (const float*)d_in[0];
    const float* pos      = (const float*)d_in[1];
    const int*   ei       = (const int*)  d_in[2];
    const int*   batch    = (const int*)  d_in[3];
    const float* enc_w1   = (const float*)d_in[4];
    const float* enc_b1   = (const float*)d_in[5];
    const float* enc_w2   = (const float*)d_in[6];
    const float* enc_b2   = (const float*)d_in[7];
    const float* pool_w   = (const float*)d_in[8];
    const float* pool_b   = (const float*)d_in[9];
    const float* toz_w    = (const float*)d_in[10];
    const float* toz_b    = (const float*)d_in[11];
    const float* vp_w1    = (const float*)d_in[12];
    const float* vp_b1    = (const float*)d_in[13];
    const float* vp_w2    = (const float*)d_in[14];
    const float* vp_b2    = (const float*)d_in[15];
    const float* bridge_w = (const float*)d_in[16];
    const float* bridge_b = (const float*)d_in[17];

    // workspace layout (4B units) ~25.3 MB
    int*   bucket_total  = (int*)d_ws;                       // 512
    float* pooled        = (float*)d_ws + NB;                // 32768 (zeroed w/ totals)
    int*   bucket_base   = (int*)d_ws + NB + 32768;          // 512
    int*   bucket_cursor = bucket_base + NB;                 // 512
    int*   staged        = bucket_cursor + NB;               // 4194304
    float* nrec          = (float*)(staged + N_EDGES);       // 2097152

    float* out        = (float*)d_out;
    float* out_recon  = out;                        // 1024*32
    float* out_z      = out_recon + 1024*32;        // 1024*8
    float* out_s      = out_z + 1024*8;             // 262144*2
    float* out_forces = out_s + (size_t)N_NODES*2;  // 1024*4
    float* out_V      = out_forces + 1024*4;        // 1024

    hipMemsetAsync(d_ws, 0, (size_t)(NB + 32768) * sizeof(float), stream);

    pack_kernel       <<<N_NODES/256, 256, 0, stream>>>(x, pos, nrec);
    bucket_hist_kernel<<<256, 256, 0, stream>>>(ei, bucket_total);
    bucket_scan_kernel<<<1, 512, 0, stream>>>(bucket_total, bucket_base, bucket_cursor);
    binning_kernel    <<<1024, 256, 0, stream>>>(ei, bucket_cursor, staged);
    fused_bucket_kernel<<<NB, 512, 0, stream>>>(
        nrec, staged, bucket_base, bucket_total, batch,
        enc_w1, enc_b1, enc_w2, enc_b2, pool_w, pool_b, out_s, pooled);
    graph_kernel<<<NUM_GRAPHS/256, 256, 0, stream>>>(
        pooled, toz_w, toz_b, vp_w1, vp_b1, vp_w2, vp_b2,
        bridge_w, bridge_b, out_recon, out_z, out_forces, out_V);
}

// Round 5
// 475.276 us; speedup vs baseline: 1.2598x; 1.2598x over previous
//
#include <hip/hip_runtime.h>
#include <math.h>

#define N_NODES   262144
#define N_EDGES   4194304
#define NUM_GRAPHS 1024
#define NB        1024         // coarse buckets (dst >> 8)
#define BN        256          // nodes per bucket
#define CAP       6144         // LDS edge-list cap per bucket (mean 4096, +32 sigma)

static __device__ __forceinline__ float sigmoidf_(float v) {
    return 1.0f / (1.0f + __expf(-v));
}

// ---------------------------------------------------------------------------
// K1: coarse bucket histogram (dst>>8) + node record packing.
// 256 blocks x 256 thr; each block: 16384 edges hist + 1024 nodes pack.
// nrec[n] = {x0,x1,x2,x3, p0,p1,p2, 0}  (32 B aligned)
// ---------------------------------------------------------------------------
__global__ __launch_bounds__(256) void hist_pack_kernel(
    const int* __restrict__ ei, const float* __restrict__ x,
    const float* __restrict__ pos,
    int* __restrict__ bucket_total, float* __restrict__ nrec)
{
    __shared__ int cnt[NB];
    #pragma unroll
    for (int k = 0; k < 4; ++k) cnt[threadIdx.x + 256*k] = 0;
    __syncthreads();

    // pack 1024 nodes (independent of hist)
    #pragma unroll
    for (int k = 0; k < 4; ++k) {
        int n = blockIdx.x * 1024 + 256*k + threadIdx.x;
        float4 xv = *(const float4*)(x + 4*n);
        float p0 = pos[3*n], p1 = pos[3*n+1], p2 = pos[3*n+2];
        float4* o = (float4*)(nrec + 8*n);
        o[0] = xv;
        o[1] = make_float4(p0, p1, p2, 0.0f);
    }

    int base = blockIdx.x * 16384;
    #pragma unroll 4
    for (int i = 0; i < 64; ++i) {
        int dst = ei[N_EDGES + base + i*256 + threadIdx.x];
        atomicAdd(&cnt[dst >> 8], 1);
    }
    __syncthreads();
    #pragma unroll
    for (int k = 0; k < 4; ++k) {
        int idx = threadIdx.x + 256*k;
        int c = cnt[idx];
        if (c) atomicAdd(bucket_total + idx, c);
    }
}

// ---------------------------------------------------------------------------
// K2: exclusive scan of 1024 bucket totals -> bucket_base, bucket_cursor.
// ---------------------------------------------------------------------------
__global__ __launch_bounds__(1024) void bucket_scan_kernel(
    const int* __restrict__ bucket_total,
    int* __restrict__ bucket_base, int* __restrict__ bucket_cursor)
{
    int i = threadIdx.x;
    int v = bucket_total[i];
    int lane = i & 63, wid = i >> 6;
    int s = v;
    #pragma unroll
    for (int o = 1; o < 64; o <<= 1) {
        int t = __shfl_up(s, o);
        if (lane >= o) s += t;
    }
    __shared__ int ws[16];
    if (lane == 63) ws[wid] = s;
    __syncthreads();
    if (wid == 0 && lane < 16) {
        int w = ws[lane];
        int sw = w;
        #pragma unroll
        for (int o = 1; o < 16; o <<= 1) {
            int t = __shfl_up(sw, o);
            if (lane >= o) sw += t;
        }
        ws[lane] = sw - w;             // exclusive wave offsets
    }
    __syncthreads();
    int excl = ws[wid] + s - v;
    bucket_base[i]   = excl;
    bucket_cursor[i] = excl;
}

// ---------------------------------------------------------------------------
// K3: binning. 256 blocks x 256 thr x 64 edges. Pack (dst&255)<<18 | src.
// ---------------------------------------------------------------------------
__global__ __launch_bounds__(256) void binning_kernel(
    const int* __restrict__ ei, int* __restrict__ bucket_cursor,
    int* __restrict__ staged)
{
    __shared__ int cnt[NB];
    __shared__ int runbase[NB];
    #pragma unroll
    for (int k = 0; k < 4; ++k) cnt[threadIdx.x + 256*k] = 0;
    __syncthreads();

    int base = blockIdx.x * 16384;
    #pragma unroll 4
    for (int i = 0; i < 64; ++i) {
        int dst = ei[N_EDGES + base + i*256 + threadIdx.x];
        atomicAdd(&cnt[dst >> 8], 1);
    }
    __syncthreads();
    #pragma unroll
    for (int k = 0; k < 4; ++k) {
        int idx = threadIdx.x + 256*k;
        int c = cnt[idx];
        runbase[idx] = c ? atomicAdd(bucket_cursor + idx, c) : 0;
        cnt[idx] = 0;
    }
    __syncthreads();
    #pragma unroll 2
    for (int i = 0; i < 64; ++i) {
        int e   = base + i*256 + threadIdx.x;
        int src = ei[e];
        int dst = ei[N_EDGES + e];
        int bk  = dst >> 8;
        int r   = atomicAdd(&cnt[bk], 1);
        staged[runbase[bk] + r] = ((dst & 255) << 18) | src;
    }
}

// ---------------------------------------------------------------------------
// K4 (fused, per-bucket): build per-node edge lists in LDS (hist+scan+scatter),
// then node-parallel gather with register accumulation; node MLP + softmax +
// attention pooling. 1024 blocks x 256 threads, ~27.5 KB LDS -> 5 blocks/CU.
// ---------------------------------------------------------------------------
__global__ __launch_bounds__(256, 5) void fused_bucket_kernel(
    const float* __restrict__ nrec,
    const int* __restrict__ staged, const int* __restrict__ bucket_base,
    const int* __restrict__ bucket_total, const int* __restrict__ batch,
    const float* __restrict__ w1, const float* __restrict__ b1,
    const float* __restrict__ w2, const float* __restrict__ b2,
    const float* __restrict__ pw, const float* __restrict__ pb,
    float* __restrict__ s_out, float* __restrict__ pooled)
{
    __shared__ int   elist[CAP];        // per-node grouped src ids
    __shared__ int   hco[BN];           // hist -> cursor
    __shared__ int   wsum[4];
    __shared__ __align__(16) float sw1[144];
    __shared__ float sb1[16];
    __shared__ __align__(16) float sw2[256];
    __shared__ float sb2[16];
    __shared__ float spw[32];
    __shared__ float spb[2];

    int tid = threadIdx.x;
    sw2[tid] = w2[tid];
    if (tid < 144) sw1[tid] = w1[tid];
    if (tid >= 144 && tid < 160) sb1[tid - 144] = b1[tid - 144];
    if (tid >= 160 && tid < 176) sb2[tid - 160] = b2[tid - 160];
    if (tid >= 176 && tid < 208) spw[tid - 176] = pw[tid - 176];
    if (tid >= 208 && tid < 210) spb[tid - 208] = pb[tid - 208];
    hco[tid] = 0;

    int bkt   = blockIdx.x;
    int nbase = bkt * BN;
    int gbase = bucket_base[bkt];
    int ecnt  = bucket_total[bkt];
    if (ecnt > CAP) ecnt = CAP;   // statistically impossible
    __syncthreads();

    // Phase A: local histogram of dst-low over this bucket's edges
    for (int i = tid; i < ecnt; i += 256) {
        int p = staged[gbase + i];
        atomicAdd(&hco[p >> 18], 1);
    }
    __syncthreads();

    // Phase B: exclusive scan of 256 counters (1 per thread)
    int deg = hco[tid];
    int lane = tid & 63, wid = tid >> 6;
    int inc = deg;
    #pragma unroll
    for (int o = 1; o < 64; o <<= 1) {
        int t = __shfl_up(inc, o);
        if (lane >= o) inc += t;
    }
    if (lane == 63) wsum[wid] = inc;
    __syncthreads();
    int wb = 0;
    #pragma unroll
    for (int w = 0; w < 4; ++w) if (w < wid) wb += wsum[w];
    int start = wb + inc - deg;        // exclusive
    __syncthreads();
    hco[tid] = start;                  // becomes scatter cursor
    __syncthreads();

    // Phase C: scatter src ids into grouped order (re-read staged, L2-hot)
    for (int i = tid; i < ecnt; i += 256) {
        int p  = staged[gbase + i];
        int r  = atomicAdd(&hco[p >> 18], 1);
        elist[r] = p & 0x3FFFF;
    }
    __syncthreads();

    // Phase D: node-parallel gather + edge MLP, register accumulation
    int n = nbase + tid;
    float4 xd = *(const float4*)(nrec + 8*n);
    float4 pd = *(const float4*)(nrec + 8*n + 4);

    float acc[16];
    #pragma unroll
    for (int j = 0; j < 16; ++j) acc[j] = 0.0f;

    // 1-deep prefetch of src record
    int srcn = (deg > 0) ? elist[start] : 0;
    float4 xs = *(const float4*)(nrec + 8*srcn);
    float4 ps = *(const float4*)(nrec + 8*srcn + 4);

    for (int k = 0; k < deg; ++k) {
        float4 cxs = xs, cps = ps;
        if (k + 1 < deg) {
            int sn = elist[start + k + 1];
            xs = *(const float4*)(nrec + 8*sn);
            ps = *(const float4*)(nrec + 8*sn + 4);
        }
        float px = cps.x - pd.x;
        float py = cps.y - pd.y;
        float pz = cps.z - pd.z;
        float dist = sqrtf(px*px + py*py + pz*pz);
        float feat[9] = {xd.x, xd.y, xd.z, xd.w, cxs.x, cxs.y, cxs.z, cxs.w, dist};

        float h[16];
        #pragma unroll
        for (int j = 0; j < 16; ++j) h[j] = sb1[j];
        #pragma unroll
        for (int q = 0; q < 9; ++q) {
            float f = feat[q];
            #pragma unroll
            for (int j4 = 0; j4 < 4; ++j4) {
                float4 w = *(const float4*)&sw1[q*16 + 4*j4];
                h[4*j4+0] = fmaf(f, w.x, h[4*j4+0]);
                h[4*j4+1] = fmaf(f, w.y, h[4*j4+1]);
                h[4*j4+2] = fmaf(f, w.z, h[4*j4+2]);
                h[4*j4+3] = fmaf(f, w.w, h[4*j4+3]);
            }
        }
        #pragma unroll
        for (int j = 0; j < 16; ++j) acc[j] = fmaf(h[j], sigmoidf_(h[j]), acc[j]);
    }

    // Phase E: node MLP + softmax + pooling
    float c = (float)deg;
    float inv = 1.0f / fmaxf(c, 1.0f);
    float h[16];
    #pragma unroll
    for (int j = 0; j < 16; ++j) h[j] = c * sb2[j];
    #pragma unroll
    for (int q = 0; q < 16; ++q) {
        float f = acc[q];
        #pragma unroll
        for (int j4 = 0; j4 < 4; ++j4) {
            float4 w = *(const float4*)&sw2[q*16 + 4*j4];
            h[4*j4+0] = fmaf(f, w.x, h[4*j4+0]);
            h[4*j4+1] = fmaf(f, w.y, h[4*j4+1]);
            h[4*j4+2] = fmaf(f, w.z, h[4*j4+2]);
            h[4*j4+3] = fmaf(f, w.w, h[4*j4+3]);
        }
    }
    #pragma unroll
    for (int j = 0; j < 16; ++j) h[j] = fmaxf(h[j] * inv, 0.0f);

    float l0 = spb[0], l1 = spb[1];
    #pragma unroll
    for (int j = 0; j < 16; ++j) {
        l0 = fmaf(h[j], spw[2*j+0], l0);
        l1 = fmaf(h[j], spw[2*j+1], l1);
    }
    float m = fmaxf(l0, l1);
    float e0 = __expf(l0 - m), e1 = __expf(l1 - m);
    float r = 1.0f / (e0 + e1);
    float s0 = e0 * r, s1 = e1 * r;
    *(float2*)(s_out + 2*n) = make_float2(s0, s1);

    float w[32];
    #pragma unroll
    for (int j = 0; j < 16; ++j) { w[j] = s0 * h[j]; w[16+j] = s1 * h[j]; }

    int b = batch[n];
    #pragma unroll
    for (int o = 1; o < 64; o <<= 1) {
        int bn = __shfl_down(b, o);
        bool take = (lane + o < 64) && (bn == b);
        #pragma unroll
        for (int cc = 0; cc < 32; ++cc) {
            float vn = __shfl_down(w[cc], o);
            if (take) w[cc] += vn;
        }
    }
    int bp = __shfl_up(b, 1);
    if (lane == 0 || bp != b) {
        float* pg = pooled + 32*b;
        #pragma unroll
        for (int cc = 0; cc < 32; ++cc) unsafeAtomicAdd(pg + cc, w[cc]);
    }
}

// ---------------------------------------------------------------------------
// K5: per-graph heads. z, recon, analytic potential + forces.
// ---------------------------------------------------------------------------
__global__ __launch_bounds__(256) void graph_kernel(
    const float* __restrict__ pooled,
    const float* __restrict__ toz_w, const float* __restrict__ toz_b,
    const float* __restrict__ vp_w1, const float* __restrict__ vp_b1,
    const float* __restrict__ vp_w2, const float* __restrict__ vp_b2,
    const float* __restrict__ bridge_w, const float* __restrict__ bridge_b,
    float* __restrict__ out_recon, float* __restrict__ out_z,
    float* __restrict__ out_forces, float* __restrict__ out_V)
{
    int g = blockIdx.x * 256 + threadIdx.x;
    if (g >= NUM_GRAPHS) return;

    const float* P = pooled + 32*g;
    float z[8];
    #pragma unroll
    for (int k = 0; k < 2; ++k) {
        #pragma unroll
        for (int d = 0; d < 4; ++d) {
            float a = toz_b[d];
            #pragma unroll
            for (int i = 0; i < 16; ++i) a = fmaf(P[16*k+i], toz_w[4*i+d], a);
            z[4*k+d] = a;
        }
    }
    #pragma unroll
    for (int i = 0; i < 8; ++i) out_z[8*g+i] = z[i];

    #pragma unroll
    for (int j = 0; j < 32; ++j) {
        float a = bridge_b[j];
        #pragma unroll
        for (int i = 0; i < 8; ++i) a = fmaf(z[i], bridge_w[32*i+j], a);
        out_recon[32*g+j] = a;
    }

    float d0 = z[0]-z[4], d1 = z[1]-z[5];
    float dd = sqrtf(d0*d0 + d1*d1 + 1e-6f);

    float V = vp_b2[0];
    float dV = 0.0f;
    #pragma unroll
    for (int j = 0; j < 32; ++j) {
        float w1 = vp_w1[j];
        float t  = fmaf(dd, w1, vp_b1[j]);
        float et = __expf(t);
        float sp = __logf(1.0f + et);
        float sg = et / (1.0f + et);
        float w2 = vp_w2[j];
        V  = fmaf(sp, w2, V);
        dV = fmaf(sg * w1, w2, dV);
    }
    out_V[g] = V;

    float scale = dV / dd;
    float gx = scale * d0, gy = scale * d1;
    out_forces[4*g+0] = -gx;
    out_forces[4*g+1] = -gy;
    out_forces[4*g+2] =  gx;
    out_forces[4*g+3] =  gy;
}

// ---------------------------------------------------------------------------
extern "C" void kernel_launch(void* const* d_in, const int* in_sizes, int n_in,
                              void* d_out, int out_size, void* d_ws, size_t ws_size,
                              hipStream_t stream) {
    const float* x        = (const float*)d_in[0];
    const float* pos      = (const float*)d_in[1];
    const int*   ei       = (const int*)  d_in[2];
    const int*   batch    = (const int*)  d_in[3];
    const float* enc_w1   = (const float*)d_in[4];
    const float* enc_b1   = (const float*)d_in[5];
    const float* enc_w2   = (const float*)d_in[6];
    const float* enc_b2   = (const float*)d_in[7];
    const float* pool_w   = (const float*)d_in[8];
    const float* pool_b   = (const float*)d_in[9];
    const float* toz_w    = (const float*)d_in[10];
    const float* toz_b    = (const float*)d_in[11];
    const float* vp_w1    = (const float*)d_in[12];
    const float* vp_b1    = (const float*)d_in[13];
    const float* vp_w2    = (const float*)d_in[14];
    const float* vp_b2    = (const float*)d_in[15];
    const float* bridge_w = (const float*)d_in[16];
    const float* bridge_b = (const float*)d_in[17];

    // workspace layout (4B units) ~25.3 MB
    int*   bucket_total  = (int*)d_ws;                       // 1024
    float* pooled        = (float*)d_ws + NB;                // 32768 (zeroed w/ totals)
    int*   bucket_base   = (int*)d_ws + NB + 32768;          // 1024
    int*   bucket_cursor = bucket_base + NB;                 // 1024
    int*   staged        = bucket_cursor + NB;               // 4194304
    float* nrec          = (float*)(staged + N_EDGES);       // 2097152

    float* out        = (float*)d_out;
    float* out_recon  = out;                        // 1024*32
    float* out_z      = out_recon + 1024*32;        // 1024*8
    float* out_s      = out_z + 1024*8;             // 262144*2
    float* out_forces = out_s + (size_t)N_NODES*2;  // 1024*4
    float* out_V      = out_forces + 1024*4;        // 1024

    hipMemsetAsync(d_ws, 0, (size_t)(NB + 32768) * sizeof(float), stream);

    hist_pack_kernel  <<<256, 256, 0, stream>>>(ei, x, pos, bucket_total, nrec);
    bucket_scan_kernel<<<1, 1024, 0, stream>>>(bucket_total, bucket_base, bucket_cursor);
    binning_kernel    <<<256, 256, 0, stream>>>(ei, bucket_cursor, staged);
    fused_bucket_kernel<<<NB, 256, 0, stream>>>(
        nrec, staged, bucket_base, bucket_total, batch,
        enc_w1, enc_b1, enc_w2, enc_b2, pool_w, pool_b, out_s, pooled);
    graph_kernel<<<NUM_GRAPHS/256, 256, 0, stream>>>(
        pooled, toz_w, toz_b, vp_w1, vp_b1, vp_w2, vp_b2,
        bridge_w, bridge_b, out_recon, out_z, out_forces, out_V);
}

// Round 6
// 440.701 us; speedup vs baseline: 1.3587x; 1.0785x over previous
//
#include <hip/hip_runtime.h>
#include <math.h>

#define N_NODES   262144
#define N_EDGES   4194304
#define NUM_GRAPHS 1024
#define NB        1024         // coarse buckets (dst >> 8)
#define BN        256          // nodes per bucket
#define CAP       6144         // LDS edge-list cap per bucket (mean 4096, +32 sigma)

typedef _Float16 h16;
typedef __attribute__((ext_vector_type(8))) _Float16 half8;

static __device__ __forceinline__ float sigmoidf_(float v) {
    return 1.0f / (1.0f + __expf(-v));
}

// ---------------------------------------------------------------------------
// K1: coarse bucket histogram (dst>>8) + fp16 node record packing.
// 256 blocks x 256 thr; each block: 16384 edges hist + 1024 nodes pack.
// nrec[n] = fp16 {x0,x1,x2,x3, p0,p1,p2, 0}  (16 B aligned)
// ---------------------------------------------------------------------------
__global__ __launch_bounds__(256) void hist_pack_kernel(
    const int* __restrict__ ei, const float* __restrict__ x,
    const float* __restrict__ pos,
    int* __restrict__ bucket_total, h16* __restrict__ nrec)
{
    __shared__ int cnt[NB];
    #pragma unroll
    for (int k = 0; k < 4; ++k) cnt[threadIdx.x + 256*k] = 0;
    __syncthreads();

    // pack 1024 nodes (independent of hist)
    #pragma unroll
    for (int k = 0; k < 4; ++k) {
        int n = blockIdx.x * 1024 + 256*k + threadIdx.x;
        float4 xv = *(const float4*)(x + 4*n);
        float p0 = pos[3*n], p1 = pos[3*n+1], p2 = pos[3*n+2];
        half8 r;
        r[0] = (h16)xv.x; r[1] = (h16)xv.y; r[2] = (h16)xv.z; r[3] = (h16)xv.w;
        r[4] = (h16)p0;   r[5] = (h16)p1;   r[6] = (h16)p2;   r[7] = (h16)0.0f;
        *(half8*)(nrec + 8*n) = r;
    }

    int base = blockIdx.x * 16384;
    #pragma unroll 4
    for (int i = 0; i < 64; ++i) {
        int dst = ei[N_EDGES + base + i*256 + threadIdx.x];
        atomicAdd(&cnt[dst >> 8], 1);
    }
    __syncthreads();
    #pragma unroll
    for (int k = 0; k < 4; ++k) {
        int idx = threadIdx.x + 256*k;
        int c = cnt[idx];
        if (c) atomicAdd(bucket_total + idx, c);
    }
}

// ---------------------------------------------------------------------------
// K2: exclusive scan of 1024 bucket totals -> bucket_base, bucket_cursor.
// ---------------------------------------------------------------------------
__global__ __launch_bounds__(1024) void bucket_scan_kernel(
    const int* __restrict__ bucket_total,
    int* __restrict__ bucket_base, int* __restrict__ bucket_cursor)
{
    int i = threadIdx.x;
    int v = bucket_total[i];
    int lane = i & 63, wid = i >> 6;
    int s = v;
    #pragma unroll
    for (int o = 1; o < 64; o <<= 1) {
        int t = __shfl_up(s, o);
        if (lane >= o) s += t;
    }
    __shared__ int ws[16];
    if (lane == 63) ws[wid] = s;
    __syncthreads();
    if (wid == 0 && lane < 16) {
        int w = ws[lane];
        int sw = w;
        #pragma unroll
        for (int o = 1; o < 16; o <<= 1) {
            int t = __shfl_up(sw, o);
            if (lane >= o) sw += t;
        }
        ws[lane] = sw - w;             // exclusive wave offsets
    }
    __syncthreads();
    int excl = ws[wid] + s - v;
    bucket_base[i]   = excl;
    bucket_cursor[i] = excl;
}

// ---------------------------------------------------------------------------
// K3: binning. 256 blocks x 256 thr x 64 edges. Pack (dst&255)<<18 | src.
// ---------------------------------------------------------------------------
__global__ __launch_bounds__(256) void binning_kernel(
    const int* __restrict__ ei, int* __restrict__ bucket_cursor,
    int* __restrict__ staged)
{
    __shared__ int cnt[NB];
    __shared__ int runbase[NB];
    #pragma unroll
    for (int k = 0; k < 4; ++k) cnt[threadIdx.x + 256*k] = 0;
    __syncthreads();

    int base = blockIdx.x * 16384;
    #pragma unroll 4
    for (int i = 0; i < 64; ++i) {
        int dst = ei[N_EDGES + base + i*256 + threadIdx.x];
        atomicAdd(&cnt[dst >> 8], 1);
    }
    __syncthreads();
    #pragma unroll
    for (int k = 0; k < 4; ++k) {
        int idx = threadIdx.x + 256*k;
        int c = cnt[idx];
        runbase[idx] = c ? atomicAdd(bucket_cursor + idx, c) : 0;
        cnt[idx] = 0;
    }
    __syncthreads();
    #pragma unroll 2
    for (int i = 0; i < 64; ++i) {
        int e   = base + i*256 + threadIdx.x;
        int src = ei[e];
        int dst = ei[N_EDGES + e];
        int bk  = dst >> 8;
        int r   = atomicAdd(&cnt[bk], 1);
        staged[runbase[bk] + r] = ((dst & 255) << 18) | src;
    }
}

// ---------------------------------------------------------------------------
// K4 (fused, per-bucket): build per-node edge lists in LDS (hist+scan+scatter),
// then node-parallel gather with register accumulation; node MLP + softmax +
// attention pooling. 1024 blocks x 256 threads, ~27.5 KB LDS -> 5 blocks/CU.
// ---------------------------------------------------------------------------
__global__ __launch_bounds__(256, 5) void fused_bucket_kernel(
    const h16* __restrict__ nrec,
    const int* __restrict__ staged, const int* __restrict__ bucket_base,
    const int* __restrict__ bucket_total, const int* __restrict__ batch,
    const float* __restrict__ w1, const float* __restrict__ b1,
    const float* __restrict__ w2, const float* __restrict__ b2,
    const float* __restrict__ pw, const float* __restrict__ pb,
    float* __restrict__ s_out, float* __restrict__ pooled)
{
    __shared__ int   elist[CAP];        // per-node grouped src ids
    __shared__ int   hco[BN];           // hist -> cursor
    __shared__ int   wsum[4];
    __shared__ __align__(16) float sw1[144];
    __shared__ float sb1[16];
    __shared__ __align__(16) float sw2[256];
    __shared__ float sb2[16];
    __shared__ float spw[32];
    __shared__ float spb[2];

    int tid = threadIdx.x;
    sw2[tid] = w2[tid];
    if (tid < 144) sw1[tid] = w1[tid];
    if (tid >= 144 && tid < 160) sb1[tid - 144] = b1[tid - 144];
    if (tid >= 160 && tid < 176) sb2[tid - 160] = b2[tid - 160];
    if (tid >= 176 && tid < 208) spw[tid - 176] = pw[tid - 176];
    if (tid >= 208 && tid < 210) spb[tid - 208] = pb[tid - 208];
    hco[tid] = 0;

    int bkt   = blockIdx.x;
    int nbase = bkt * BN;
    int gbase = bucket_base[bkt];
    int ecnt  = bucket_total[bkt];
    if (ecnt > CAP) ecnt = CAP;   // statistically impossible
    __syncthreads();

    // Phase A: local histogram of dst-low over this bucket's edges
    for (int i = tid; i < ecnt; i += 256) {
        int p = staged[gbase + i];
        atomicAdd(&hco[p >> 18], 1);
    }
    __syncthreads();

    // Phase B: exclusive scan of 256 counters (1 per thread)
    int deg = hco[tid];
    int lane = tid & 63, wid = tid >> 6;
    int inc = deg;
    #pragma unroll
    for (int o = 1; o < 64; o <<= 1) {
        int t = __shfl_up(inc, o);
        if (lane >= o) inc += t;
    }
    if (lane == 63) wsum[wid] = inc;
    __syncthreads();
    int wb = 0;
    #pragma unroll
    for (int w = 0; w < 4; ++w) if (w < wid) wb += wsum[w];
    int start = wb + inc - deg;        // exclusive
    __syncthreads();
    hco[tid] = start;                  // becomes scatter cursor
    __syncthreads();

    // Phase C: scatter src ids into grouped order (re-read staged, L2-hot)
    for (int i = tid; i < ecnt; i += 256) {
        int p  = staged[gbase + i];
        int r  = atomicAdd(&hco[p >> 18], 1);
        elist[r] = p & 0x3FFFF;
    }
    __syncthreads();

    // Phase D: node-parallel gather + edge MLP, register accumulation
    int n = nbase + tid;
    half8 rd = *(const half8*)(nrec + 8*n);
    float xd0 = (float)rd[0], xd1 = (float)rd[1], xd2 = (float)rd[2], xd3 = (float)rd[3];
    float pdx = (float)rd[4], pdy = (float)rd[5], pdz = (float)rd[6];

    float acc[16];
    #pragma unroll
    for (int j = 0; j < 16; ++j) acc[j] = 0.0f;

    // 1-deep prefetch of src record
    int srcn = (deg > 0) ? elist[start] : 0;
    half8 rs = *(const half8*)(nrec + 8*srcn);

    for (int k = 0; k < deg; ++k) {
        half8 cr = rs;
        if (k + 1 < deg) {
            int sn = elist[start + k + 1];
            rs = *(const half8*)(nrec + 8*sn);
        }
        float px = (float)cr[4] - pdx;
        float py = (float)cr[5] - pdy;
        float pz = (float)cr[6] - pdz;
        float dist = sqrtf(px*px + py*py + pz*pz);
        float feat[9] = {xd0, xd1, xd2, xd3,
                         (float)cr[0], (float)cr[1], (float)cr[2], (float)cr[3],
                         dist};

        float h[16];
        #pragma unroll
        for (int j = 0; j < 16; ++j) h[j] = sb1[j];
        #pragma unroll
        for (int q = 0; q < 9; ++q) {
            float f = feat[q];
            #pragma unroll
            for (int j4 = 0; j4 < 4; ++j4) {
                float4 w = *(const float4*)&sw1[q*16 + 4*j4];
                h[4*j4+0] = fmaf(f, w.x, h[4*j4+0]);
                h[4*j4+1] = fmaf(f, w.y, h[4*j4+1]);
                h[4*j4+2] = fmaf(f, w.z, h[4*j4+2]);
                h[4*j4+3] = fmaf(f, w.w, h[4*j4+3]);
            }
        }
        #pragma unroll
        for (int j = 0; j < 16; ++j) acc[j] = fmaf(h[j], sigmoidf_(h[j]), acc[j]);
    }

    // Phase E: node MLP + softmax + pooling
    float c = (float)deg;
    float inv = 1.0f / fmaxf(c, 1.0f);
    float h[16];
    #pragma unroll
    for (int j = 0; j < 16; ++j) h[j] = c * sb2[j];
    #pragma unroll
    for (int q = 0; q < 16; ++q) {
        float f = acc[q];
        #pragma unroll
        for (int j4 = 0; j4 < 4; ++j4) {
            float4 w = *(const float4*)&sw2[q*16 + 4*j4];
            h[4*j4+0] = fmaf(f, w.x, h[4*j4+0]);
            h[4*j4+1] = fmaf(f, w.y, h[4*j4+1]);
            h[4*j4+2] = fmaf(f, w.z, h[4*j4+2]);
            h[4*j4+3] = fmaf(f, w.w, h[4*j4+3]);
        }
    }
    #pragma unroll
    for (int j = 0; j < 16; ++j) h[j] = fmaxf(h[j] * inv, 0.0f);

    float l0 = spb[0], l1 = spb[1];
    #pragma unroll
    for (int j = 0; j < 16; ++j) {
        l0 = fmaf(h[j], spw[2*j+0], l0);
        l1 = fmaf(h[j], spw[2*j+1], l1);
    }
    float m = fmaxf(l0, l1);
    float e0 = __expf(l0 - m), e1 = __expf(l1 - m);
    float r = 1.0f / (e0 + e1);
    float s0 = e0 * r, s1 = e1 * r;
    *(float2*)(s_out + 2*n) = make_float2(s0, s1);

    float w[32];
    #pragma unroll
    for (int j = 0; j < 16; ++j) { w[j] = s0 * h[j]; w[16+j] = s1 * h[j]; }

    int b = batch[n];
    #pragma unroll
    for (int o = 1; o < 64; o <<= 1) {
        int bn = __shfl_down(b, o);
        bool take = (lane + o < 64) && (bn == b);
        #pragma unroll
        for (int cc = 0; cc < 32; ++cc) {
            float vn = __shfl_down(w[cc], o);
            if (take) w[cc] += vn;
        }
    }
    int bp = __shfl_up(b, 1);
    if (lane == 0 || bp != b) {
        float* pg = pooled + 32*b;
        #pragma unroll
        for (int cc = 0; cc < 32; ++cc) unsafeAtomicAdd(pg + cc, w[cc]);
    }
}

// ---------------------------------------------------------------------------
// K5: per-graph heads. z, recon, analytic potential + forces.
// ---------------------------------------------------------------------------
__global__ __launch_bounds__(256) void graph_kernel(
    const float* __restrict__ pooled,
    const float* __restrict__ toz_w, const float* __restrict__ toz_b,
    const float* __restrict__ vp_w1, const float* __restrict__ vp_b1,
    const float* __restrict__ vp_w2, const float* __restrict__ vp_b2,
    const float* __restrict__ bridge_w, const float* __restrict__ bridge_b,
    float* __restrict__ out_recon, float* __restrict__ out_z,
    float* __restrict__ out_forces, float* __restrict__ out_V)
{
    int g = blockIdx.x * 256 + threadIdx.x;
    if (g >= NUM_GRAPHS) return;

    const float* P = pooled + 32*g;
    float z[8];
    #pragma unroll
    for (int k = 0; k < 2; ++k) {
        #pragma unroll
        for (int d = 0; d < 4; ++d) {
            float a = toz_b[d];
            #pragma unroll
            for (int i = 0; i < 16; ++i) a = fmaf(P[16*k+i], toz_w[4*i+d], a);
            z[4*k+d] = a;
        }
    }
    #pragma unroll
    for (int i = 0; i < 8; ++i) out_z[8*g+i] = z[i];

    #pragma unroll
    for (int j = 0; j < 32; ++j) {
        float a = bridge_b[j];
        #pragma unroll
        for (int i = 0; i < 8; ++i) a = fmaf(z[i], bridge_w[32*i+j], a);
        out_recon[32*g+j] = a;
    }

    float d0 = z[0]-z[4], d1 = z[1]-z[5];
    float dd = sqrtf(d0*d0 + d1*d1 + 1e-6f);

    float V = vp_b2[0];
    float dV = 0.0f;
    #pragma unroll
    for (int j = 0; j < 32; ++j) {
        float w1 = vp_w1[j];
        float t  = fmaf(dd, w1, vp_b1[j]);
        float et = __expf(t);
        float sp = __logf(1.0f + et);
        float sg = et / (1.0f + et);
        float w2 = vp_w2[j];
        V  = fmaf(sp, w2, V);
        dV = fmaf(sg * w1, w2, dV);
    }
    out_V[g] = V;

    float scale = dV / dd;
    float gx = scale * d0, gy = scale * d1;
    out_forces[4*g+0] = -gx;
    out_forces[4*g+1] = -gy;
    out_forces[4*g+2] =  gx;
    out_forces[4*g+3] =  gy;
}

// ---------------------------------------------------------------------------
extern "C" void kernel_launch(void* const* d_in, const int* in_sizes, int n_in,
                              void* d_out, int out_size, void* d_ws, size_t ws_size,
                              hipStream_t stream) {
    const float* x        = (const float*)d_in[0];
    const float* pos      = (const float*)d_in[1];
    const int*   ei       = (const int*)  d_in[2];
    const int*   batch    = (const int*)  d_in[3];
    const float* enc_w1   = (const float*)d_in[4];
    const float* enc_b1   = (const float*)d_in[5];
    const float* enc_w2   = (const float*)d_in[6];
    const float* enc_b2   = (const float*)d_in[7];
    const float* pool_w   = (const float*)d_in[8];
    const float* pool_b   = (const float*)d_in[9];
    const float* toz_w    = (const float*)d_in[10];
    const float* toz_b    = (const float*)d_in[11];
    const float* vp_w1    = (const float*)d_in[12];
    const float* vp_b1    = (const float*)d_in[13];
    const float* vp_w2    = (const float*)d_in[14];
    const float* vp_b2    = (const float*)d_in[15];
    const float* bridge_w = (const float*)d_in[16];
    const float* bridge_b = (const float*)d_in[17];

    // workspace layout (4B units) ~21.3 MB
    int*   bucket_total  = (int*)d_ws;                       // 1024
    float* pooled        = (float*)d_ws + NB;                // 32768 (zeroed w/ totals)
    int*   bucket_base   = (int*)d_ws + NB + 32768;          // 1024
    int*   bucket_cursor = bucket_base + NB;                 // 1024
    int*   staged        = bucket_cursor + NB;               // 4194304
    h16*   nrec          = (h16*)(staged + N_EDGES);         // 262144*8 fp16 = 4 MB

    float* out        = (float*)d_out;
    float* out_recon  = out;                        // 1024*32
    float* out_z      = out_recon + 1024*32;        // 1024*8
    float* out_s      = out_z + 1024*8;             // 262144*2
    float* out_forces = out_s + (size_t)N_NODES*2;  // 1024*4
    float* out_V      = out_forces + 1024*4;        // 1024

    hipMemsetAsync(d_ws, 0, (size_t)(NB + 32768) * sizeof(float), stream);

    hist_pack_kernel  <<<256, 256, 0, stream>>>(ei, x, pos, bucket_total, nrec);
    bucket_scan_kernel<<<1, 1024, 0, stream>>>(bucket_total, bucket_base, bucket_cursor);
    binning_kernel    <<<256, 256, 0, stream>>>(ei, bucket_cursor, staged);
    fused_bucket_kernel<<<NB, 256, 0, stream>>>(
        nrec, staged, bucket_base, bucket_total, batch,
        enc_w1, enc_b1, enc_w2, enc_b2, pool_w, pool_b, out_s, pooled);
    graph_kernel<<<NUM_GRAPHS/256, 256, 0, stream>>>(
        pooled, toz_w, toz_b, vp_w1, vp_b1, vp_w2, vp_b2,
        bridge_w, bridge_b, out_recon, out_z, out_forces, out_V);
}